// Round 1
// baseline (174.780 us; speedup 1.0000x reference)
//
#include <hip/hip_runtime.h>

#define HW      (1024 * 1024)
#define HW4     (HW / 4)
#define NBINS   4096
#define NIMG    9                 // 8 input images + 1 style
#define BPI     128               // 1152 hist blocks: all co-resident, 1.11x tail
#define THREADS 256
#define F4_PER_BLOCK (HW4 / BPI)  // 2048 float4 per block per channel
#define NSTAGE  (F4_PER_BLOCK / (2 * THREADS))  // 4 pipeline stages
#define RBLOCKS 256               // reduce blocks, 16 bins each

typedef float f4 __attribute__((ext_vector_type(4)));

// Exact searchsorted(boundaries, x, 'left'), boundaries b_j = (j+1)/8 - 1.
// Branchless binary search, exact float compares (verified absmax 0.0).
__device__ __forceinline__ int bin16(float x) {
    int lo = 0;
    if (0.0f < x) lo = 8;
    if ((float)(lo + 4) * 0.125f - 1.0f < x) lo += 4;
    if ((float)(lo + 2) * 0.125f - 1.0f < x) lo += 2;
    if ((float)(lo + 1) * 0.125f - 1.0f < x) lo += 1;
    return lo;
}

__device__ __forceinline__ int bin3(float r, float g, float b) {
    return bin16(r) + 16 * bin16(g) + 256 * bin16(b);
}

__device__ __forceinline__ void acc4(int* lh, f4 r, f4 g, f4 b) {
    atomicAdd(&lh[bin3(r.x, g.x, b.x)], 1);
    atomicAdd(&lh[bin3(r.y, g.y, b.y)], 1);
    atomicAdd(&lh[bin3(r.z, g.z, b.z)], 1);
    atomicAdd(&lh[bin3(r.w, g.w, b.w)], 1);
}

// Per-block LDS histogram, explicitly software-pipelined: stage s+1's six
// float4 loads issue BEFORE stage s is consumed, so global-load latency
// overlaps the bin+ds_add chain. No device atomics, no fences, no zeroing.
__global__ __launch_bounds__(THREADS, 4) void hist_kernel(
        const float* __restrict__ input,        // [8,3,HW]
        const float* __restrict__ style,        // [1,3,HW]
        unsigned short* __restrict__ part,      // [NIMG][BPI][NBINS] u16
        int* __restrict__ gstate) {             // [2]: {loss_sum, ticket}
    __shared__ int lh[NBINS];                   // 16 KB
    const int img = blockIdx.y;
    const int blk = blockIdx.x;
    // Reset the fused reducer's accumulator/ticket for this graph iteration.
    // Kernel-boundary release/acquire makes this visible to reduce_loss.
    if (img == 8 && blk == 0 && threadIdx.x == 0) {
        gstate[0] = 0;
        gstate[1] = 0;
    }
    const float* base = (img < 8) ? (input + (size_t)img * 3 * HW) : style;

    for (int i = threadIdx.x; i < NBINS; i += THREADS) lh[i] = 0;
    __syncthreads();

    const f4* c0 = (const f4*)(base);
    const f4* c1 = (const f4*)(base + HW);
    const f4* c2 = (const f4*)(base + 2 * HW);
    const int start = blk * F4_PER_BLOCK + threadIdx.x;

    f4 buf[2][6];
    auto load_stage = [&](int s, f4* d) {
        const int p0 = start + s * 2 * THREADS;
        const int p1 = p0 + THREADS;
        d[0] = c0[p0]; d[1] = c1[p0]; d[2] = c2[p0];
        d[3] = c0[p1]; d[4] = c1[p1]; d[5] = c2[p1];
    };

    load_stage(0, buf[0]);
#pragma unroll
    for (int s = 0; s < NSTAGE; ++s) {
        if (s + 1 < NSTAGE) load_stage(s + 1, buf[(s + 1) & 1]);
        f4* d = buf[s & 1];
        acc4(lh, d[0], d[1], d[2]);
        acc4(lh, d[3], d[4], d[5]);
    }
    __syncthreads();

    // Flush: pack 8 counts -> uint4 (16 B/thread/iter), 2 iters.
    uint4* dst = (uint4*)(part + ((size_t)img * BPI + blk) * NBINS);
    for (int i = threadIdx.x; i < NBINS / 8; i += THREADS) {
        uint4 v;
        v.x = (unsigned)lh[8 * i]     | ((unsigned)lh[8 * i + 1] << 16);
        v.y = (unsigned)lh[8 * i + 2] | ((unsigned)lh[8 * i + 3] << 16);
        v.z = (unsigned)lh[8 * i + 4] | ((unsigned)lh[8 * i + 5] << 16);
        v.w = (unsigned)lh[8 * i + 6] | ((unsigned)lh[8 * i + 7] << 16);
        dst[i] = v;
    }
}

// Fused reduce + |diff| + final: block owns 16 bins. 3 latency phases
// (style; imgs 0-3 one per wave; imgs 4-7 one per wave) instead of 9
// serialized steps. Loads are uint4 = 8 packed-u16 partials; packed adds of
// up to 4 partials are carry-safe (4*8192 = 32768 < 65536). A 5-round
// __shfl_xor butterfly over the 32 partial-lanes finishes each bin sum.
// Last block (device-atomic ticket) writes the final loss -> no 3rd kernel.
__global__ __launch_bounds__(THREADS) void reduce_loss_kernel(
        const unsigned short* __restrict__ part,  // [NIMG][BPI][NBINS]
        int* __restrict__ gstate,                 // [2]: {loss_sum, ticket}
        float* __restrict__ out) {
    __shared__ int tred[4][16];
    __shared__ int tgt[16];
    __shared__ int warr[4];
    const int lane = threadIdx.x & 63;
    const int w    = threadIdx.x >> 6;   // wave 0..3
    const int c    = lane & 1;           // 8-bin chunk within block's 16 bins
    const int p    = lane >> 1;          // partial-lane 0..31
    const int b0   = blockIdx.x * 16;

    auto qptr = [&](int img, int pg) {
        return (const uint4*)(part + ((size_t)(img * BPI + pg) * NBINS)
                              + b0 + 8 * c);
    };

    // Phase 0: style image -> per-bin target. Waves split the 128 partials.
    {
        uint4 v = *qptr(8, p + 32 * w);
        int v8[8];
        v8[0] = v.x & 0xFFFF; v8[1] = v.x >> 16;
        v8[2] = v.y & 0xFFFF; v8[3] = v.y >> 16;
        v8[4] = v.z & 0xFFFF; v8[5] = v.z >> 16;
        v8[6] = v.w & 0xFFFF; v8[7] = v.w >> 16;
#pragma unroll
        for (int m = 2; m <= 32; m <<= 1) {
#pragma unroll
            for (int i = 0; i < 8; ++i) v8[i] += __shfl_xor(v8[i], m, 64);
        }
        if (lane < 2) {
#pragma unroll
            for (int i = 0; i < 8; ++i) tred[w][8 * c + i] = v8[i];
        }
    }
    __syncthreads();
    if (threadIdx.x < 16) {
        tgt[threadIdx.x] = tred[0][threadIdx.x] + tred[1][threadIdx.x]
                         + tred[2][threadIdx.x] + tred[3][threadIdx.x];
    }
    __syncthreads();

    // Phases 1-2: wave w handles images w and w+4. All 128 partials per wave:
    // 4 uint4 loads per lane, packed-add, unpack, butterfly over p.
    int acc = 0;
#pragma unroll
    for (int ph = 0; ph < 2; ++ph) {
        const int img = w + 4 * ph;
        uint4 a  = *qptr(img, p);
        uint4 b  = *qptr(img, p + 32);
        uint4 cc = *qptr(img, p + 64);
        uint4 d  = *qptr(img, p + 96);
        uint4 s;
        s.x = a.x + b.x + cc.x + d.x;   // packed u16 pair, carry-safe
        s.y = a.y + b.y + cc.y + d.y;
        s.z = a.z + b.z + cc.z + d.z;
        s.w = a.w + b.w + cc.w + d.w;
        int v8[8];
        v8[0] = s.x & 0xFFFF; v8[1] = s.x >> 16;
        v8[2] = s.y & 0xFFFF; v8[3] = s.y >> 16;
        v8[4] = s.z & 0xFFFF; v8[5] = s.z >> 16;
        v8[6] = s.w & 0xFFFF; v8[7] = s.w >> 16;
#pragma unroll
        for (int m = 2; m <= 32; m <<= 1) {
#pragma unroll
            for (int i = 0; i < 8; ++i) v8[i] += __shfl_xor(v8[i], m, 64);
        }
        if (lane < 2) {
#pragma unroll
            for (int i = 0; i < 8; ++i) {
                const int dd = v8[i] - tgt[8 * c + i];
                acc += (dd < 0) ? -dd : dd;
            }
        }
    }

    // acc lives on lanes 0,1 of each wave (0 elsewhere).
    acc += __shfl_xor(acc, 1, 64);
    if (lane == 0) warr[w] = acc;
    __syncthreads();
    if (threadIdx.x == 0) {
        const int bacc = warr[0] + warr[1] + warr[2] + warr[3];
        atomicAdd(&gstate[0], bacc);
        __threadfence();
        const int old = atomicAdd(&gstate[1], 1);
        if (old == RBLOCKS - 1) {
            // All 256 partial sums are in; S <= 16.8M, /2^35 is exact.
            const int total = atomicAdd(&gstate[0], 0);
            out[0] = (float)((double)total / 34359738368.0);
        }
    }
}

extern "C" void kernel_launch(void* const* d_in, const int* in_sizes, int n_in,
                              void* d_out, int out_size, void* d_ws, size_t ws_size,
                              hipStream_t stream) {
    const float* input = (const float*)d_in[0];  // [8,3,1024,1024]
    const float* style = (const float*)d_in[1];  // [1,3,1024,1024]
    unsigned short* part = (unsigned short*)d_ws;   // 9*128*4096 u16 = 9.44 MB
    int* gstate = (int*)((char*)d_ws +
                         (size_t)NIMG * BPI * NBINS * sizeof(unsigned short));

    hipLaunchKernelGGL(hist_kernel, dim3(BPI, NIMG), dim3(THREADS), 0, stream,
                       input, style, part, gstate);
    hipLaunchKernelGGL(reduce_loss_kernel, dim3(RBLOCKS), dim3(THREADS),
                       0, stream, part, gstate, (float*)d_out);
}

// Round 2
// 169.433 us; speedup vs baseline: 1.0316x; 1.0316x over previous
//
#include <hip/hip_runtime.h>

#define HW      (1024 * 1024)
#define HW4     (HW / 4)
#define NBINS   4096
#define NIMG    9                 // 8 input images + 1 style
#define BPI     128               // 1152 hist blocks: all co-resident, 1.11x tail
#define THREADS 256
#define F4_PER_BLOCK (HW4 / BPI)  // 2048 float4 per block per channel
#define NSTAGE  (F4_PER_BLOCK / (2 * THREADS))  // 4 pipeline stages
#define RBLOCKS 256               // reduce blocks, 16 bins each

typedef float f4 __attribute__((ext_vector_type(4)));

// Exact searchsorted(boundaries, x, 'left'), boundaries b_j = (j+1)/8 - 1.
// Branchless binary search, exact float compares (verified absmax 0.0).
__device__ __forceinline__ int bin16(float x) {
    int lo = 0;
    if (0.0f < x) lo = 8;
    if ((float)(lo + 4) * 0.125f - 1.0f < x) lo += 4;
    if ((float)(lo + 2) * 0.125f - 1.0f < x) lo += 2;
    if ((float)(lo + 1) * 0.125f - 1.0f < x) lo += 1;
    return lo;
}

__device__ __forceinline__ int bin3(float r, float g, float b) {
    return bin16(r) + 16 * bin16(g) + 256 * bin16(b);
}

__device__ __forceinline__ void acc4(int* lh, f4 r, f4 g, f4 b) {
    atomicAdd(&lh[bin3(r.x, g.x, b.x)], 1);
    atomicAdd(&lh[bin3(r.y, g.y, b.y)], 1);
    atomicAdd(&lh[bin3(r.z, g.z, b.z)], 1);
    atomicAdd(&lh[bin3(r.w, g.w, b.w)], 1);
}

// Per-block LDS histogram, explicitly software-pipelined: stage s+1's six
// float4 loads issue BEFORE stage s is consumed, so global-load latency
// overlaps the bin+ds_add chain. No device atomics, no fences, no zeroing.
__global__ __launch_bounds__(THREADS, 4) void hist_kernel(
        const float* __restrict__ input,        // [8,3,HW]
        const float* __restrict__ style,        // [1,3,HW]
        unsigned short* __restrict__ part,      // [NIMG][BPI][NBINS] u16
        unsigned long long* __restrict__ gsum) {// packed {count<<40 | loss}
    __shared__ int lh[NBINS];                   // 16 KB
    const int img = blockIdx.y;
    const int blk = blockIdx.x;
    // Reset the fused reducer's packed accumulator for this graph iteration.
    // Kernel-boundary release/acquire makes this visible to reduce_loss.
    if (img == 8 && blk == 0 && threadIdx.x == 0) *gsum = 0ULL;
    const float* base = (img < 8) ? (input + (size_t)img * 3 * HW) : style;

    for (int i = threadIdx.x; i < NBINS; i += THREADS) lh[i] = 0;
    __syncthreads();

    const f4* c0 = (const f4*)(base);
    const f4* c1 = (const f4*)(base + HW);
    const f4* c2 = (const f4*)(base + 2 * HW);
    const int start = blk * F4_PER_BLOCK + threadIdx.x;

    f4 buf[2][6];
    auto load_stage = [&](int s, f4* d) {
        const int p0 = start + s * 2 * THREADS;
        const int p1 = p0 + THREADS;
        d[0] = c0[p0]; d[1] = c1[p0]; d[2] = c2[p0];
        d[3] = c0[p1]; d[4] = c1[p1]; d[5] = c2[p1];
    };

    load_stage(0, buf[0]);
#pragma unroll
    for (int s = 0; s < NSTAGE; ++s) {
        if (s + 1 < NSTAGE) load_stage(s + 1, buf[(s + 1) & 1]);
        f4* d = buf[s & 1];
        acc4(lh, d[0], d[1], d[2]);
        acc4(lh, d[3], d[4], d[5]);
    }
    __syncthreads();

    // Flush: pack 8 counts -> uint4 (16 B/thread/iter), 2 iters.
    uint4* dst = (uint4*)(part + ((size_t)img * BPI + blk) * NBINS);
    for (int i = threadIdx.x; i < NBINS / 8; i += THREADS) {
        uint4 v;
        v.x = (unsigned)lh[8 * i]     | ((unsigned)lh[8 * i + 1] << 16);
        v.y = (unsigned)lh[8 * i + 2] | ((unsigned)lh[8 * i + 3] << 16);
        v.z = (unsigned)lh[8 * i + 4] | ((unsigned)lh[8 * i + 5] << 16);
        v.w = (unsigned)lh[8 * i + 6] | ((unsigned)lh[8 * i + 7] << 16);
        dst[i] = v;
    }
}

// Fused reduce + |diff| + final: block owns 16 bins. 3 latency phases
// (style; imgs 0-3 one per wave; imgs 4-7 one per wave). Loads are uint4 =
// 8 packed-u16 partials; packed adds of up to 4 partials are carry-safe
// (4*8192 = 32768 < 65536). A 5-round __shfl_xor butterfly over the 32
// partial-lanes finishes each bin sum. Completion detection: ONE packed
// 64-bit atomicAdd per block (loss in bits 0..39, block-count at bit 40).
// The 256th block's RETURN VALUE already holds the other 255 partials, so
// no __threadfence / ticket / re-read is needed (that fence chain cost
// ~6 us in R1).
__global__ __launch_bounds__(THREADS) void reduce_loss_kernel(
        const unsigned short* __restrict__ part,  // [NIMG][BPI][NBINS]
        unsigned long long* __restrict__ gsum,    // packed {count<<40 | loss}
        float* __restrict__ out) {
    __shared__ int tred[4][16];
    __shared__ int tgt[16];
    __shared__ int warr[4];
    const int lane = threadIdx.x & 63;
    const int w    = threadIdx.x >> 6;   // wave 0..3
    const int c    = lane & 1;           // 8-bin chunk within block's 16 bins
    const int p    = lane >> 1;          // partial-lane 0..31
    const int b0   = blockIdx.x * 16;

    auto qptr = [&](int img, int pg) {
        return (const uint4*)(part + ((size_t)(img * BPI + pg) * NBINS)
                              + b0 + 8 * c);
    };

    // Phase 0: style image -> per-bin target. Waves split the 128 partials.
    {
        uint4 v = *qptr(8, p + 32 * w);
        int v8[8];
        v8[0] = v.x & 0xFFFF; v8[1] = v.x >> 16;
        v8[2] = v.y & 0xFFFF; v8[3] = v.y >> 16;
        v8[4] = v.z & 0xFFFF; v8[5] = v.z >> 16;
        v8[6] = v.w & 0xFFFF; v8[7] = v.w >> 16;
#pragma unroll
        for (int m = 2; m <= 32; m <<= 1) {
#pragma unroll
            for (int i = 0; i < 8; ++i) v8[i] += __shfl_xor(v8[i], m, 64);
        }
        if (lane < 2) {
#pragma unroll
            for (int i = 0; i < 8; ++i) tred[w][8 * c + i] = v8[i];
        }
    }
    __syncthreads();
    if (threadIdx.x < 16) {
        tgt[threadIdx.x] = tred[0][threadIdx.x] + tred[1][threadIdx.x]
                         + tred[2][threadIdx.x] + tred[3][threadIdx.x];
    }
    __syncthreads();

    // Phases 1-2: wave w handles images w and w+4. All 128 partials per wave:
    // 4 uint4 loads per lane, packed-add, unpack, butterfly over p.
    int acc = 0;
#pragma unroll
    for (int ph = 0; ph < 2; ++ph) {
        const int img = w + 4 * ph;
        uint4 a  = *qptr(img, p);
        uint4 b  = *qptr(img, p + 32);
        uint4 cc = *qptr(img, p + 64);
        uint4 d  = *qptr(img, p + 96);
        uint4 s;
        s.x = a.x + b.x + cc.x + d.x;   // packed u16 pair, carry-safe
        s.y = a.y + b.y + cc.y + d.y;
        s.z = a.z + b.z + cc.z + d.z;
        s.w = a.w + b.w + cc.w + d.w;
        int v8[8];
        v8[0] = s.x & 0xFFFF; v8[1] = s.x >> 16;
        v8[2] = s.y & 0xFFFF; v8[3] = s.y >> 16;
        v8[4] = s.z & 0xFFFF; v8[5] = s.z >> 16;
        v8[6] = s.w & 0xFFFF; v8[7] = s.w >> 16;
#pragma unroll
        for (int m = 2; m <= 32; m <<= 1) {
#pragma unroll
            for (int i = 0; i < 8; ++i) v8[i] += __shfl_xor(v8[i], m, 64);
        }
        if (lane < 2) {
#pragma unroll
            for (int i = 0; i < 8; ++i) {
                const int dd = v8[i] - tgt[8 * c + i];
                acc += (dd < 0) ? -dd : dd;
            }
        }
    }

    // acc lives on lanes 0,1 of each wave (0 elsewhere).
    acc += __shfl_xor(acc, 1, 64);
    if (lane == 0) warr[w] = acc;
    __syncthreads();
    if (threadIdx.x == 0) {
        const unsigned long long bacc =
            (unsigned long long)(warr[0] + warr[1] + warr[2] + warr[3]);
        // Packed: loss in bits 0..39 (sum <= 16.8M < 2^25), count at bit 40.
        const unsigned long long old =
            atomicAdd(gsum, bacc + (1ULL << 40));
        if ((old >> 40) == RBLOCKS - 1) {
            const unsigned long long total =
                (old & ((1ULL << 40) - 1)) + bacc;
            // S <= 16.8M, /2^35 is exact in double.
            out[0] = (float)((double)total / 34359738368.0);
        }
    }
}

extern "C" void kernel_launch(void* const* d_in, const int* in_sizes, int n_in,
                              void* d_out, int out_size, void* d_ws, size_t ws_size,
                              hipStream_t stream) {
    const float* input = (const float*)d_in[0];  // [8,3,1024,1024]
    const float* style = (const float*)d_in[1];  // [1,3,1024,1024]
    unsigned short* part = (unsigned short*)d_ws;   // 9*128*4096 u16 = 9.44 MB
    unsigned long long* gsum = (unsigned long long*)((char*)d_ws +
                        (size_t)NIMG * BPI * NBINS * sizeof(unsigned short));

    hipLaunchKernelGGL(hist_kernel, dim3(BPI, NIMG), dim3(THREADS), 0, stream,
                       input, style, part, gsum);
    hipLaunchKernelGGL(reduce_loss_kernel, dim3(RBLOCKS), dim3(THREADS),
                       0, stream, part, gsum, (float*)d_out);
}